// Round 1
// baseline (403.108 us; speedup 1.0000x reference)
//
#include <hip/hip_runtime.h>
#include <stdint.h>

#define N_IMG 32
#define C_IN 256
#define K_OUT 256
#define HW 56
#define HP 58
#define SPATIAL (N_IMG*HW*HW)          /* 100352 */
#define KDIM (C_IN*9)                  /* 2304 */
#define XPAD_ELEMS (N_IMG*HP*HP*C_IN)  /* 27557888 */
#define XPAD_BYTES (XPAD_ELEMS*2)      /* 55115776 */
#define WT_BYTES (K_OUT*KDIM*2)        /* 1179648 */
#define OUT_ELEMS (N_IMG*K_OUT*HW*HW)  /* 25690112 */

typedef __bf16 bf16x8 __attribute__((ext_vector_type(8)));
typedef float  f32x4  __attribute__((ext_vector_type(4)));

static __device__ __forceinline__ unsigned short f2bf(float f) {
    unsigned u = __float_as_uint(f);
    u += 0x7fff + ((u >> 16) & 1);   // RNE
    return (unsigned short)(u >> 16);
}

static __device__ __forceinline__ void gld16(const void* g, void* l) {
    __builtin_amdgcn_global_load_lds(
        (const __attribute__((address_space(1))) void*)g,
        (__attribute__((address_space(3))) void*)l, 16, 0, 0);
}

// ---------------- pass 1: zero the padded buffer ----------------
__global__ void zero_xpad(uint4* __restrict__ p) {
    int i = blockIdx.x * 256 + threadIdx.x;
    if (i < XPAD_BYTES / 16) p[i] = make_uint4(0u, 0u, 0u, 0u);
}

// ---------------- pass 2: x fp32 NCHW -> bf16 NHWC padded ----------------
// one block per (h, n); LDS-transpose c<->w
__global__ void transform_x(const float* __restrict__ x,
                            unsigned short* __restrict__ xpad) {
    __shared__ unsigned short lds[HW][264];   // +8 pad
    const int h = blockIdx.x, n = blockIdx.y;
    const int t = threadIdx.x;
    const int w = t & 63, cg = t >> 6;        // cg in 0..3
    if (w < HW) {
        const float* xp = x + ((n * C_IN + cg) * HW + h) * HW + w;
        #pragma unroll 4
        for (int cc = 0; cc < C_IN; cc += 4)
            lds[w][cc + cg] = f2bf(xp[cc * (HW * HW)]);
    }
    __syncthreads();
    const int wr = t >> 5;            // 0..7
    const int c8 = (t & 31) * 8;      // c chunk
    for (int i = 0; i < 7; ++i) {
        int ww = i * 8 + wr;
        uint4 v = *(const uint4*)&lds[ww][c8];
        *(uint4*)&xpad[((n * HP + (h + 1)) * HP + (ww + 1)) * C_IN + c8] = v;
    }
}

// ---------------- pass 3: W fp32 OIHW -> bf16 [k][rs][c] ----------------
__global__ void transform_w(const float* __restrict__ W,
                            unsigned short* __restrict__ Wt) {
    const int k = blockIdx.x, c = threadIdx.x;
    const float* wp = W + (k * C_IN + c) * 9;
    #pragma unroll
    for (int rs = 0; rs < 9; ++rs)
        Wt[k * KDIM + rs * C_IN + c] = f2bf(wp[rs]);
}

// ---------------- main: implicit GEMM, 128x128 tile, bf16 MFMA ----------------
__global__ __launch_bounds__(256) void conv_gemm(
    const unsigned short* __restrict__ xpad,
    const unsigned short* __restrict__ Wt,
    float* __restrict__ out) {
    __shared__ char smem[16384];      // A: [0,8K) 128x32 bf16 ; B: [8K,16K) 128x32 bf16
    const int t = threadIdx.x;
    const int w0 = t >> 6, l = t & 63;
    const int p0 = blockIdx.x * 128;  // spatial tile
    const int m0 = blockIdx.y * 128;  // out-channel tile

    // ---- staging source addresses (constant over K-loop) ----
    const int cq = l & 3;                       // 16B chunk within 64B row
    const int row0 = w0 * 32 + (l >> 2);        // LDS tile row, issue 0
    const int row1 = row0 + 16;                 // issue 1
    int pb[2];
    {
        const int rows[2] = {row0, row1};
        #pragma unroll
        for (int i = 0; i < 2; ++i) {
            int p = p0 + rows[i];
            int n = p / 3136; int rem = p - n * 3136;
            int h = rem / 56; int ww = rem - h * 56;
            pb[i] = ((n * HP + h) * HP + ww) * C_IN + cq * 8;  // r=s=0 base
        }
    }
    const int wa0 = (m0 + row0) * KDIM + cq * 8;
    const int wa1 = (m0 + row1) * KDIM + cq * 8;

    // ---- LDS staging destinations (wave-uniform base; HW adds lane*16) ----
    char* ldsA0 = smem + w0 * 2048;
    char* ldsA1 = smem + w0 * 2048 + 1024;
    char* ldsB0 = smem + 8192 + w0 * 2048;
    char* ldsB1 = smem + 8192 + w0 * 2048 + 1024;

    // ---- fragment read offsets (constant over K-loop) ----
    const int lm = l & 15, lq = l >> 4;
    const int mw = w0 & 1, pw = w0 >> 1;
    int offA[4], offB[4];
    #pragma unroll
    for (int i = 0; i < 4; ++i) {
        offA[i] = (mw * 64 + i * 16 + lm) * 64 + lq * 16;
        offB[i] = 8192 + (pw * 64 + i * 16 + lm) * 64 + lq * 16;
    }

    f32x4 acc[4][4] = {};

    for (int step = 0; step < 72; ++step) {
        const int k0 = step * 32;
        const int rs = k0 >> 8;           // 0..8, (r,s) of this K-slice
        const int c0 = k0 & 255;
        const int r = rs / 3, s = rs - r * 3;
        const int offx = (r * HP + s) * C_IN + c0;
        gld16(Wt + wa0 + k0, ldsA0);
        gld16(Wt + wa1 + k0, ldsA1);
        gld16(xpad + pb[0] + offx, ldsB0);
        gld16(xpad + pb[1] + offx, ldsB1);
        __syncthreads();
        bf16x8 a[4], b[4];
        #pragma unroll
        for (int i = 0; i < 4; ++i) {
            a[i] = *(const bf16x8*)(smem + offA[i]);
            b[i] = *(const bf16x8*)(smem + offB[i]);
        }
        #pragma unroll
        for (int ti = 0; ti < 4; ++ti)
            #pragma unroll
            for (int tj = 0; tj < 4; ++tj)
                acc[ti][tj] = __builtin_amdgcn_mfma_f32_16x16x32_bf16(
                    a[ti], b[tj], acc[ti][tj], 0, 0, 0);
        __syncthreads();
    }

    // ---- epilogue: C/D layout col=lane&15 (spatial), row=lq*4+r (out-ch) ----
    int obase[4];
    #pragma unroll
    for (int tj = 0; tj < 4; ++tj) {
        int p = p0 + pw * 64 + tj * 16 + lm;
        int n = p / 3136; int rem = p - n * 3136;
        int h = rem / 56; int ww = rem - h * 56;
        obase[tj] = n * (K_OUT * 3136) + h * 56 + ww;
    }
    const int kb = m0 + mw * 64 + lq * 4;
    #pragma unroll
    for (int ti = 0; ti < 4; ++ti)
        #pragma unroll
        for (int tj = 0; tj < 4; ++tj) {
            float* op = out + obase[tj] + (kb + ti * 16) * 3136;
            #pragma unroll
            for (int r2 = 0; r2 < 4; ++r2)
                op[r2 * 3136] = acc[ti][tj][r2];
        }
}

// ---------------- fallback (only if ws too small): naive fp32 direct conv ----------------
__global__ void conv_naive(const float* __restrict__ x, const float* __restrict__ W,
                           float* __restrict__ out, int total) {
    int idx = blockIdx.x * 256 + threadIdx.x;
    if (idx >= total) return;
    int n = idx / (K_OUT * 3136); int rem = idx - n * (K_OUT * 3136);
    int k = rem / 3136; rem -= k * 3136;
    int h = rem / 56; int w = rem - h * 56;
    float acc = 0.f;
    for (int c = 0; c < C_IN; ++c) {
        const float* xp = x + ((n * C_IN + c) * HW) * HW;
        const float* wp = W + (k * C_IN + c) * 9;
        #pragma unroll
        for (int r = 0; r < 3; ++r) {
            int hh = h + r - 1;
            if ((unsigned)hh >= HW) continue;
            #pragma unroll
            for (int s = 0; s < 3; ++s) {
                int ww = w + s - 1;
                if ((unsigned)ww >= HW) continue;
                acc += xp[hh * HW + ww] * wp[r * 3 + s];
            }
        }
    }
    out[idx] = acc;
}

extern "C" void kernel_launch(void* const* d_in, const int* in_sizes, int n_in,
                              void* d_out, int out_size, void* d_ws, size_t ws_size,
                              hipStream_t stream) {
    const float* x = (const float*)d_in[0];
    const float* W = (const float*)d_in[1];
    float* out = (float*)d_out;
    const size_t need = (size_t)XPAD_BYTES + WT_BYTES;
    if (ws_size >= need) {
        unsigned short* xpad = (unsigned short*)d_ws;
        unsigned short* Wt = (unsigned short*)((char*)d_ws + XPAD_BYTES);
        zero_xpad<<<(XPAD_BYTES / 16 + 255) / 256, 256, 0, stream>>>((uint4*)d_ws);
        transform_x<<<dim3(HW, N_IMG), 256, 0, stream>>>(x, xpad);
        transform_w<<<K_OUT, 256, 0, stream>>>(W, (unsigned short*)Wt);
        conv_gemm<<<dim3(SPATIAL / 128, 2), 256, 0, stream>>>(xpad, Wt, out);
    } else {
        conv_naive<<<(OUT_ELEMS + 255) / 256, 256, 0, stream>>>(x, W, out, OUT_ELEMS);
    }
}

// Round 2
// 361.996 us; speedup vs baseline: 1.1136x; 1.1136x over previous
//
#include <hip/hip_runtime.h>
#include <stdint.h>

#define N_IMG 32
#define C_IN 256
#define K_OUT 256
#define HW 56
#define HP 58
#define SPATIAL (N_IMG*HW*HW)          /* 100352 */
#define KDIM (C_IN*9)                  /* 2304 */
#define XPAD_ELEMS (N_IMG*HP*HP*C_IN)  /* 27557888 */
#define XPAD_BYTES (XPAD_ELEMS*2)      /* 55115776 */
#define WT_BYTES (K_OUT*KDIM*2)        /* 1179648 */
#define OUT_ELEMS (N_IMG*K_OUT*HW*HW)  /* 25690112 */
#define BK 64

typedef __bf16 bf16x8 __attribute__((ext_vector_type(8)));
typedef float  f32x4  __attribute__((ext_vector_type(4)));

static __device__ __forceinline__ unsigned short f2bf(float f) {
    unsigned u = __float_as_uint(f);
    u += 0x7fff + ((u >> 16) & 1);   // RNE
    return (unsigned short)(u >> 16);
}

static __device__ __forceinline__ void gld16(const void* g, void* l) {
    __builtin_amdgcn_global_load_lds(
        (const __attribute__((address_space(1))) void*)g,
        (__attribute__((address_space(3))) void*)l, 16, 0, 0);
}

// ---------------- pass 1: zero ONLY the pad border (3.7 MB, not 55 MB) ----------------
// border cells per image: h in {0,57} full rows (2*58) + w in {0,57} for h 1..56 (2*56) = 228
__global__ void zero_border(unsigned short* __restrict__ xpad) {
    int idx = blockIdx.x * 256 + threadIdx.x;   // one thread per uint4 (8 shorts)
    int cell = idx >> 5, q = idx & 31;          // 32 uint4 per cell (256 ch)
    if (cell >= N_IMG * 228) return;
    int n = cell / 228, r = cell - n * 228;
    int h, w;
    if (r < 58)       { h = 0;            w = r; }
    else if (r < 116) { h = 57;           w = r - 58; }
    else if (r < 172) { h = r - 116 + 1;  w = 0; }
    else              { h = r - 172 + 1;  w = 57; }
    uint4 z = make_uint4(0u, 0u, 0u, 0u);
    *(uint4*)&xpad[((n * HP + h) * HP + w) * C_IN + q * 8] = z;
}

// ---------------- pass 2: x fp32 NCHW -> bf16 NHWC padded interior ----------------
__global__ void transform_x(const float* __restrict__ x,
                            unsigned short* __restrict__ xpad) {
    __shared__ unsigned short lds[HW][264];   // +8 pad
    const int h = blockIdx.x, n = blockIdx.y;
    const int t = threadIdx.x;
    const int w = t & 63, cg = t >> 6;        // cg in 0..3
    if (w < HW) {
        const float* xp = x + ((n * C_IN + cg) * HW + h) * HW + w;
        #pragma unroll 4
        for (int cc = 0; cc < C_IN; cc += 4)
            lds[w][cc + cg] = f2bf(xp[cc * (HW * HW)]);
    }
    __syncthreads();
    const int wr = t >> 5;            // 0..7
    const int c8 = (t & 31) * 8;      // c chunk
    for (int i = 0; i < 7; ++i) {
        int ww = i * 8 + wr;
        uint4 v = *(const uint4*)&lds[ww][c8];
        *(uint4*)&xpad[((n * HP + (h + 1)) * HP + (ww + 1)) * C_IN + c8] = v;
    }
}

// ---------------- pass 3: W fp32 OIHW -> bf16 [k][rs][c] ----------------
__global__ void transform_w(const float* __restrict__ W,
                            unsigned short* __restrict__ Wt) {
    const int k = blockIdx.x, c = threadIdx.x;
    const float* wp = W + (k * C_IN + c) * 9;
    #pragma unroll
    for (int rs = 0; rs < 9; ++rs)
        Wt[k * KDIM + rs * C_IN + c] = f2bf(wp[rs]);
}

// ---------------- main: implicit GEMM, 128x128 tile, BK=64, swizzled LDS ----------------
// LDS tile rows are 128 B = 8 chunks of 16 B. A chunk holding logical k-chunk
// `lc` of row `r` is stored at physical slot (lc ^ (r&7)) — keeps staging
// lane-linear (base + lane*16) while making fragment ds_read_b128 hit all 32
// banks (fixes the 1.4e7 bank-conflict cycles of the 64-B-row layout).
__global__ __launch_bounds__(256) void conv_gemm(
    const unsigned short* __restrict__ xpad,
    const unsigned short* __restrict__ Wt,
    float* __restrict__ out) {
    __shared__ __align__(16) char smem[32768];  // A:[0,16K) 128x64 bf16; B:[16K,32K)
    const int t = threadIdx.x;
    const int w0 = t >> 6, l = t & 63;
    const int p0 = blockIdx.x * 128;  // spatial tile
    const int m0 = blockIdx.y * 128;  // out-channel tile

    // ---- staging constants: per issue, 8 rows x 8 chunks; lane l -> row +(l>>3),
    // physical chunk (l&7); it fetches logical chunk (l&7)^(l>>3) ----
    const int lr = l >> 3;
    const int lc = (l & 7) ^ lr;      // logical chunk this lane fetches
    int aSrc[4], bSrc[4];
    #pragma unroll
    for (int i = 0; i < 4; ++i) {
        const int row = w0 * 32 + i * 8 + lr;
        aSrc[i] = (m0 + row) * KDIM + lc * 8;
        int p = p0 + row;
        int n = p / 3136; int rem = p - n * 3136;
        int h = rem / 56; int ww = rem - h * 56;
        bSrc[i] = ((n * HP + h) * HP + ww) * C_IN + lc * 8;  // r=s=0 base (padded coords)
    }

    // ---- fragment read offsets ----
    const int lm = l & 15, lq = l >> 4;
    const int mw = w0 & 1, pw = w0 >> 1;
    int rowA[4], rowB[4];
    #pragma unroll
    for (int i = 0; i < 4; ++i) {
        rowA[i] = (mw * 64 + i * 16 + lm) * 128;
        rowB[i] = 16384 + (pw * 64 + i * 16 + lm) * 128;
    }

    f32x4 acc[4][4] = {};

    for (int step = 0; step < KDIM / BK; ++step) {
        const int k0 = step * BK;
        const int rs = k0 >> 8;           // 0..8
        const int c0 = k0 & 255;          // 0,64,128,192
        const int r = rs / 3, s = rs - r * 3;
        const int offx = (r * HP + s) * C_IN + c0;
        #pragma unroll
        for (int i = 0; i < 4; ++i)
            gld16(Wt + aSrc[i] + k0, smem + (w0 * 32 + i * 8) * 128);
        #pragma unroll
        for (int i = 0; i < 4; ++i)
            gld16(xpad + bSrc[i] + offx, smem + 16384 + (w0 * 32 + i * 8) * 128);
        __syncthreads();
        #pragma unroll
        for (int kk = 0; kk < 2; ++kk) {
            const int ch = ((kk * 4 + lq) ^ (l & 7)) * 16;
            bf16x8 a[4], b[4];
            #pragma unroll
            for (int i = 0; i < 4; ++i) {
                a[i] = *(const bf16x8*)(smem + rowA[i] + ch);
                b[i] = *(const bf16x8*)(smem + rowB[i] + ch);
            }
            #pragma unroll
            for (int ti = 0; ti < 4; ++ti)
                #pragma unroll
                for (int tj = 0; tj < 4; ++tj)
                    acc[ti][tj] = __builtin_amdgcn_mfma_f32_16x16x32_bf16(
                        a[ti], b[tj], acc[ti][tj], 0, 0, 0);
        }
        __syncthreads();
    }

    // ---- epilogue: C/D layout col=lane&15 (spatial), row=lq*4+r2 (out-ch) ----
    int obase[4];
    #pragma unroll
    for (int tj = 0; tj < 4; ++tj) {
        int p = p0 + pw * 64 + tj * 16 + lm;
        int n = p / 3136; int rem = p - n * 3136;
        int h = rem / 56; int ww = rem - h * 56;
        obase[tj] = n * (K_OUT * 3136) + h * 56 + ww;
    }
    const int kb = m0 + mw * 64 + lq * 4;
    #pragma unroll
    for (int ti = 0; ti < 4; ++ti)
        #pragma unroll
        for (int tj = 0; tj < 4; ++tj) {
            float* op = out + obase[tj] + (kb + ti * 16) * 3136;
            #pragma unroll
            for (int r2 = 0; r2 < 4; ++r2)
                op[r2 * 3136] = acc[ti][tj][r2];
        }
}

// ---------------- fallback (only if ws too small): naive fp32 direct conv ----------------
__global__ void conv_naive(const float* __restrict__ x, const float* __restrict__ W,
                           float* __restrict__ out, int total) {
    int idx = blockIdx.x * 256 + threadIdx.x;
    if (idx >= total) return;
    int n = idx / (K_OUT * 3136); int rem = idx - n * (K_OUT * 3136);
    int k = rem / 3136; rem -= k * 3136;
    int h = rem / 56; int w = rem - h * 56;
    float acc = 0.f;
    for (int c = 0; c < C_IN; ++c) {
        const float* xp = x + ((n * C_IN + c) * HW) * HW;
        const float* wp = W + (k * C_IN + c) * 9;
        #pragma unroll
        for (int r = 0; r < 3; ++r) {
            int hh = h + r - 1;
            if ((unsigned)hh >= HW) continue;
            #pragma unroll
            for (int s = 0; s < 3; ++s) {
                int ww = w + s - 1;
                if ((unsigned)ww >= HW) continue;
                acc += xp[hh * HW + ww] * wp[r * 3 + s];
            }
        }
    }
    out[idx] = acc;
}

extern "C" void kernel_launch(void* const* d_in, const int* in_sizes, int n_in,
                              void* d_out, int out_size, void* d_ws, size_t ws_size,
                              hipStream_t stream) {
    const float* x = (const float*)d_in[0];
    const float* W = (const float*)d_in[1];
    float* out = (float*)d_out;
    const size_t need = (size_t)XPAD_BYTES + WT_BYTES;
    if (ws_size >= need) {
        unsigned short* xpad = (unsigned short*)d_ws;
        unsigned short* Wt = (unsigned short*)((char*)d_ws + XPAD_BYTES);
        zero_border<<<(N_IMG * 228 * 32 + 255) / 256, 256, 0, stream>>>(xpad);
        transform_x<<<dim3(HW, N_IMG), 256, 0, stream>>>(x, xpad);
        transform_w<<<K_OUT, 256, 0, stream>>>(W, Wt);
        conv_gemm<<<dim3(SPATIAL / 128, 2), 256, 0, stream>>>(xpad, Wt, out);
    } else {
        conv_naive<<<(OUT_ELEMS + 255) / 256, 256, 0, stream>>>(x, W, out, OUT_ELEMS);
    }
}

// Round 3
// 305.302 us; speedup vs baseline: 1.3204x; 1.1857x over previous
//
#include <hip/hip_runtime.h>
#include <stdint.h>

#define N_IMG 32
#define C_IN 256
#define K_OUT 256
#define HW 56
#define HP 58
#define SPATIAL (N_IMG*HW*HW)          /* 100352 */
#define KDIM (C_IN*9)                  /* 2304 */
#define XPAD_ELEMS (N_IMG*HP*HP*C_IN)  /* 27557888 */
#define XPAD_BYTES (XPAD_ELEMS*2)      /* 55115776 */
#define WT_BYTES (K_OUT*KDIM*2)        /* 1179648 */
#define OUT_ELEMS (N_IMG*K_OUT*HW*HW)  /* 25690112 */
#define BK 64

/* prep grid partition */
#define PREP_X_BLOCKS (HW*N_IMG)            /* 1792 */
#define PREP_Z_BLOCKS ((N_IMG*228*32)/256)  /* 912: border uint4s */
#define PREP_W_BLOCKS K_OUT                 /* 256 */
#define PREP_BLOCKS (PREP_X_BLOCKS+PREP_Z_BLOCKS+PREP_W_BLOCKS)

typedef __bf16 bf16x8 __attribute__((ext_vector_type(8)));
typedef float  f32x4  __attribute__((ext_vector_type(4)));

static __device__ __forceinline__ unsigned short f2bf(float f) {
    unsigned u = __float_as_uint(f);
    u += 0x7fff + ((u >> 16) & 1);   // RNE
    return (unsigned short)(u >> 16);
}

static __device__ __forceinline__ void gld16(const void* g, void* l) {
    __builtin_amdgcn_global_load_lds(
        (const __attribute__((address_space(1))) void*)g,
        (__attribute__((address_space(3))) void*)l, 16, 0, 0);
}

// ---------------- fused prep: x->NHWC bf16 padded, border zero, W transform ----
__global__ __launch_bounds__(256) void prep(
    const float* __restrict__ x, const float* __restrict__ W,
    unsigned short* __restrict__ xpad, unsigned short* __restrict__ Wt) {
    const int b = blockIdx.x, t = threadIdx.x;
    if (b < PREP_X_BLOCKS) {
        // ---- x fp32 NCHW -> bf16 NHWC interior, XOR-swizzled LDS transpose ----
        __shared__ unsigned short lds[HW][C_IN];   // 28 KB; 16-B chunk c is at slot c^(w&31)
        const int h = b % HW, n = b / HW;
        const int w = t & 63, cg = t >> 6;         // cg: which 64-channel group
        if (w < HW) {
            const float* xp = x + ((n * C_IN + cg * 64) * HW + h) * HW + w;
            #pragma unroll
            for (int c8 = 0; c8 < 8; ++c8) {
                unsigned short v[8];
                #pragma unroll
                for (int j = 0; j < 8; ++j)
                    v[j] = f2bf(xp[(c8 * 8 + j) * (HW * HW)]);
                const int pc = (cg * 8 + c8) ^ (w & 31);
                *(uint4*)&lds[w][pc * 8] = *(const uint4*)v;   // conflict-free b128
            }
        }
        __syncthreads();
        const int wr = t >> 5, ci = t & 31;
        #pragma unroll
        for (int i = 0; i < 7; ++i) {
            int ww = i * 8 + wr;
            uint4 v = *(const uint4*)&lds[ww][((ci ^ (ww & 31)) * 8)];
            *(uint4*)&xpad[((n * HP + (h + 1)) * HP + (ww + 1)) * C_IN + ci * 8] = v;
        }
    } else if (b < PREP_X_BLOCKS + PREP_Z_BLOCKS) {
        // ---- zero the pad border (one uint4 per thread) ----
        int idx = (b - PREP_X_BLOCKS) * 256 + t;
        int cell = idx >> 5, q = idx & 31;
        int n = cell / 228, r = cell - n * 228;
        int h, w;
        if (r < 58)       { h = 0;            w = r; }
        else if (r < 116) { h = 57;           w = r - 58; }
        else if (r < 172) { h = r - 116 + 1;  w = 0; }
        else              { h = r - 172 + 1;  w = 57; }
        uint4 z = make_uint4(0u, 0u, 0u, 0u);
        *(uint4*)&xpad[((n * HP + h) * HP + w) * C_IN + q * 8] = z;
    } else {
        // ---- W fp32 OIHW -> bf16 [k][rs][c] ----
        const int k = b - PREP_X_BLOCKS - PREP_Z_BLOCKS, c = t;
        const float* wp = W + (k * C_IN + c) * 9;
        #pragma unroll
        for (int rs = 0; rs < 9; ++rs)
            Wt[k * KDIM + rs * C_IN + c] = f2bf(wp[rs]);
    }
}

// ---------------- main: implicit GEMM, 256(m)x128(n) tile, BK=64, swizzled LDS ----
// A = Wt [256 x 2304], B = im2col(xpad) [100352 x 2304]. One block does ALL 256
// out-channels for its 128 spatial points: halves logical B traffic vs 2 k-tiles
// and doubles MFMA work per barrier (64 MFMA/wave/step ~310 cyc between drains).
__global__ __launch_bounds__(256, 2) void conv_gemm(
    const unsigned short* __restrict__ xpad,
    const unsigned short* __restrict__ Wt,
    float* __restrict__ out) {
    __shared__ __align__(16) char smem[49152];  // A:[0,32K) 256x64 bf16; B:[32K,48K) 128x64
    const int t = threadIdx.x;
    const int w0 = t >> 6, l = t & 63;
    const int p0 = blockIdx.x * 128;  // spatial tile

    // ---- staging: per issue 8 rows x 8 chunks; lane l -> row +(l>>3), phys chunk
    // (l&7) = logical chunk ((l&7)^(l>>3)) ^ (row&7) ----
    const int lr = l >> 3;
    const int lc = (l & 7) ^ lr;      // logical chunk this lane fetches
    int aSrc[8], bSrc[4];
    #pragma unroll
    for (int i = 0; i < 8; ++i)
        aSrc[i] = (w0 * 64 + i * 8 + lr) * KDIM + lc * 8;
    #pragma unroll
    for (int i = 0; i < 4; ++i) {
        int p = p0 + w0 * 32 + i * 8 + lr;
        int n = p / 3136; int rem = p - n * 3136;
        int h = rem / 56; int ww = rem - h * 56;
        bSrc[i] = ((n * HP + h) * HP + ww) * C_IN + lc * 8;  // r=s=0 base (padded coords)
    }

    // ---- fragment read offsets: wave w0 owns m rows [w0*64, w0*64+64), all 128 n ----
    const int lm = l & 15, lq = l >> 4;
    int rowA[4], rowB[8];
    #pragma unroll
    for (int i = 0; i < 4; ++i) rowA[i] = (w0 * 64 + i * 16 + lm) * 128;
    #pragma unroll
    for (int j = 0; j < 8; ++j) rowB[j] = 32768 + (j * 16 + lm) * 128;

    f32x4 acc[4][8] = {};

    for (int step = 0; step < KDIM / BK; ++step) {
        const int k0 = step * BK;
        const int rs = k0 >> 8;           // 0..8
        const int c0 = k0 & 255;          // 0,64,128,192
        const int r = rs / 3, s = rs - r * 3;
        const int offx = (r * HP + s) * C_IN + c0;
        #pragma unroll
        for (int i = 0; i < 8; ++i)
            gld16(Wt + aSrc[i] + k0, smem + (w0 * 64 + i * 8) * 128);
        #pragma unroll
        for (int i = 0; i < 4; ++i)
            gld16(xpad + bSrc[i] + offx, smem + 32768 + (w0 * 32 + i * 8) * 128);
        __syncthreads();
        #pragma unroll
        for (int kk = 0; kk < 2; ++kk) {
            const int ch = ((kk * 4 + lq) ^ (l & 7)) * 16;   // row&7 == l&7 for all frags
            bf16x8 a[4], b[8];
            #pragma unroll
            for (int i = 0; i < 4; ++i) a[i] = *(const bf16x8*)(smem + rowA[i] + ch);
            #pragma unroll
            for (int j = 0; j < 8; ++j) b[j] = *(const bf16x8*)(smem + rowB[j] + ch);
            #pragma unroll
            for (int ti = 0; ti < 4; ++ti)
                #pragma unroll
                for (int tj = 0; tj < 8; ++tj)
                    acc[ti][tj] = __builtin_amdgcn_mfma_f32_16x16x32_bf16(
                        a[ti], b[tj], acc[ti][tj], 0, 0, 0);
        }
        __syncthreads();
    }

    // ---- epilogue: C/D layout col=lane&15 (spatial), row=lq*4+r2 (out-ch) ----
    int obase[8];
    #pragma unroll
    for (int tj = 0; tj < 8; ++tj) {
        int p = p0 + tj * 16 + lm;
        int n = p / 3136; int rem = p - n * 3136;
        int h = rem / 56; int ww = rem - h * 56;
        obase[tj] = n * (K_OUT * 3136) + h * 56 + ww;
    }
    const int kb = w0 * 64 + lq * 4;
    #pragma unroll
    for (int ti = 0; ti < 4; ++ti)
        #pragma unroll
        for (int tj = 0; tj < 8; ++tj) {
            float* op = out + obase[tj] + (kb + ti * 16) * 3136;
            #pragma unroll
            for (int r2 = 0; r2 < 4; ++r2)
                op[r2 * 3136] = acc[ti][tj][r2];
        }
}

// ---------------- fallback (only if ws too small): naive fp32 direct conv ----------------
__global__ void conv_naive(const float* __restrict__ x, const float* __restrict__ W,
                           float* __restrict__ out, int total) {
    int idx = blockIdx.x * 256 + threadIdx.x;
    if (idx >= total) return;
    int n = idx / (K_OUT * 3136); int rem = idx - n * (K_OUT * 3136);
    int k = rem / 3136; rem -= k * 3136;
    int h = rem / 56; int w = rem - h * 56;
    float acc = 0.f;
    for (int c = 0; c < C_IN; ++c) {
        const float* xp = x + ((n * C_IN + c) * HW) * HW;
        const float* wp = W + (k * C_IN + c) * 9;
        #pragma unroll
        for (int r = 0; r < 3; ++r) {
            int hh = h + r - 1;
            if ((unsigned)hh >= HW) continue;
            #pragma unroll
            for (int s = 0; s < 3; ++s) {
                int ww = w + s - 1;
                if ((unsigned)ww >= HW) continue;
                acc += xp[hh * HW + ww] * wp[r * 3 + s];
            }
        }
    }
    out[idx] = acc;
}

extern "C" void kernel_launch(void* const* d_in, const int* in_sizes, int n_in,
                              void* d_out, int out_size, void* d_ws, size_t ws_size,
                              hipStream_t stream) {
    const float* x = (const float*)d_in[0];
    const float* W = (const float*)d_in[1];
    float* out = (float*)d_out;
    const size_t need = (size_t)XPAD_BYTES + WT_BYTES;
    if (ws_size >= need) {
        unsigned short* xpad = (unsigned short*)d_ws;
        unsigned short* Wt = (unsigned short*)((char*)d_ws + XPAD_BYTES);
        prep<<<PREP_BLOCKS, 256, 0, stream>>>(x, W, xpad, Wt);
        conv_gemm<<<SPATIAL / 128, 256, 0, stream>>>(xpad, Wt, out);
    } else {
        conv_naive<<<(OUT_ELEMS + 255) / 256, 256, 0, stream>>>(x, W, out, OUT_ELEMS);
    }
}

// Round 4
// 302.399 us; speedup vs baseline: 1.3330x; 1.0096x over previous
//
#include <hip/hip_runtime.h>
#include <stdint.h>

#define N_IMG 32
#define C_IN 256
#define K_OUT 256
#define HW 56
#define HP 58
#define SPATIAL (N_IMG*HW*HW)          /* 100352 */
#define KDIM (C_IN*9)                  /* 2304 */
#define XPAD_ELEMS (N_IMG*HP*HP*C_IN)  /* 27557888 */
#define XPAD_BYTES (XPAD_ELEMS*2)      /* 55115776 */
#define WT_BYTES (K_OUT*KDIM*2)        /* 1179648 */
#define OUT_ELEMS (N_IMG*K_OUT*HW*HW)  /* 25690112 */
#define BK 64

/* prep grid partition */
#define PREP_X_BLOCKS (SPATIAL/64)          /* 1568: 64 spatial points x 256 ch each */
#define PREP_Z_BLOCKS ((N_IMG*228*32)/256)  /* 912: border uint4s */
#define PREP_W_BLOCKS K_OUT                 /* 256 */
#define PREP_BLOCKS (PREP_X_BLOCKS+PREP_Z_BLOCKS+PREP_W_BLOCKS)

typedef __bf16 bf16x8 __attribute__((ext_vector_type(8)));
typedef float  f32x4  __attribute__((ext_vector_type(4)));

static __device__ __forceinline__ unsigned short f2bf(float f) {
    unsigned u = __float_as_uint(f);
    u += 0x7fff + ((u >> 16) & 1);   // RNE
    return (unsigned short)(u >> 16);
}

static __device__ __forceinline__ void gld16(const void* g, void* l) {
    __builtin_amdgcn_global_load_lds(
        (const __attribute__((address_space(1))) void*)g,
        (__attribute__((address_space(3))) void*)l, 16, 0, 0);
}

// ---------------- fused prep: x->NHWC bf16 padded, border zero, W transform ----
// x-part: block = 64 flat spatial points of one image (3136%64==0), all 256 ch.
// Phase 1: lanes span positions (256-B coalesced reads per channel), 4 ch/thread
//   -> one 8-B LDS write into XOR-chunk-swizzled [pos][chan] tile (2x-min bank
//   aliasing = free per m136).
// Phase 2: lanes span channel-chunks -> conflict-free b128 LDS reads, perfect
//   512-B-contiguous global writes.
__global__ __launch_bounds__(256) void prep(
    const float* __restrict__ x, const float* __restrict__ W,
    unsigned short* __restrict__ xpad, unsigned short* __restrict__ Wt) {
    const int b = blockIdx.x, t = threadIdx.x;
    if (b < PREP_X_BLOCKS) {
        __shared__ __align__(16) unsigned short lds[64 * 256];   // 32 KB
        const int n = b / 49, hw0 = (b % 49) * 64;
        const int l = t & 63, w0 = t >> 6;
        const float* xbase = x + (size_t)(n * C_IN) * 3136 + hw0 + l;
        #pragma unroll
        for (int i = 0; i < 16; ++i) {
            const int c4 = w0 * 64 + i * 4;      // 4 consecutive channels
            unsigned short v[4];
            #pragma unroll
            for (int j = 0; j < 4; ++j)
                v[j] = f2bf(xbase[(c4 + j) * 3136]);
            const int m = c4 >> 3, h8 = (c4 >> 2) & 1;   // wave-uniform
            *(uint2*)&lds[l * 256 + ((m ^ (l & 31)) << 3) + h8 * 4] = *(const uint2*)v;
        }
        __syncthreads();
        const int q = t & 31;
        #pragma unroll
        for (int j = 0; j < 8; ++j) {
            const int p = (t >> 5) + j * 8;
            const int hw = hw0 + p, h = hw / 56, w = hw - h * 56;
            uint4 v = *(const uint4*)&lds[p * 256 + ((q ^ (p & 31)) << 3)];
            *(uint4*)&xpad[((n * HP + h + 1) * HP + (w + 1)) * C_IN + q * 8] = v;
        }
    } else if (b < PREP_X_BLOCKS + PREP_Z_BLOCKS) {
        // ---- zero the pad border (one uint4 per thread) ----
        int idx = (b - PREP_X_BLOCKS) * 256 + t;
        int cell = idx >> 5, qq = idx & 31;
        int n = cell / 228, r = cell - n * 228;
        int h, w;
        if (r < 58)       { h = 0;            w = r; }
        else if (r < 116) { h = 57;           w = r - 58; }
        else if (r < 172) { h = r - 116 + 1;  w = 0; }
        else              { h = r - 172 + 1;  w = 57; }
        uint4 z = make_uint4(0u, 0u, 0u, 0u);
        *(uint4*)&xpad[((n * HP + h) * HP + w) * C_IN + qq * 8] = z;
    } else {
        // ---- W fp32 OIHW -> bf16 [k][rs][c] ----
        const int k = b - PREP_X_BLOCKS - PREP_Z_BLOCKS, c = t;
        const float* wp = W + (k * C_IN + c) * 9;
        #pragma unroll
        for (int rs = 0; rs < 9; ++rs)
            Wt[k * KDIM + rs * C_IN + c] = f2bf(wp[rs]);
    }
}

// ---------------- main: implicit GEMM, 256(m)x128(n) tile, BK=64, swizzled LDS ----
// At the m97-structure plateau (904 TF-equiv, MfmaUtil 38%). XCD-contiguous
// block swizzle (784 = 8 XCDs x 98) groups adjacent spatial tiles on one XCD
// for halo/L2 reuse of xpad.
__global__ __launch_bounds__(256, 2) void conv_gemm(
    const unsigned short* __restrict__ xpad,
    const unsigned short* __restrict__ Wt,
    float* __restrict__ out) {
    __shared__ __align__(16) char smem[49152];  // A:[0,32K) 256x64 bf16; B:[32K,48K) 128x64
    const int t = threadIdx.x;
    const int w0 = t >> 6, l = t & 63;
    const int bx = blockIdx.x;
    const int p0 = ((bx & 7) * 98 + (bx >> 3)) * 128;  // spatial tile, XCD-swizzled

    // ---- staging: per issue 8 rows x 8 chunks; lane l -> row +(l>>3), phys chunk
    // (l&7) = logical chunk ((l&7)^(l>>3)) ^ (row&7) ----
    const int lr = l >> 3;
    const int lc = (l & 7) ^ lr;      // logical chunk this lane fetches
    int aSrc[8], bSrc[4];
    #pragma unroll
    for (int i = 0; i < 8; ++i)
        aSrc[i] = (w0 * 64 + i * 8 + lr) * KDIM + lc * 8;
    #pragma unroll
    for (int i = 0; i < 4; ++i) {
        int p = p0 + w0 * 32 + i * 8 + lr;
        int n = p / 3136; int rem = p - n * 3136;
        int h = rem / 56; int ww = rem - h * 56;
        bSrc[i] = ((n * HP + h) * HP + ww) * C_IN + lc * 8;  // r=s=0 base (padded coords)
    }

    // ---- fragment read offsets: wave w0 owns m rows [w0*64, w0*64+64), all 128 n ----
    const int lm = l & 15, lq = l >> 4;
    int rowA[4], rowB[8];
    #pragma unroll
    for (int i = 0; i < 4; ++i) rowA[i] = (w0 * 64 + i * 16 + lm) * 128;
    #pragma unroll
    for (int j = 0; j < 8; ++j) rowB[j] = 32768 + (j * 16 + lm) * 128;

    f32x4 acc[4][8] = {};

    for (int step = 0; step < KDIM / BK; ++step) {
        const int k0 = step * BK;
        const int rs = k0 >> 8;           // 0..8
        const int c0 = k0 & 255;          // 0,64,128,192
        const int r = rs / 3, s = rs - r * 3;
        const int offx = (r * HP + s) * C_IN + c0;
        #pragma unroll
        for (int i = 0; i < 8; ++i)
            gld16(Wt + aSrc[i] + k0, smem + (w0 * 64 + i * 8) * 128);
        #pragma unroll
        for (int i = 0; i < 4; ++i)
            gld16(xpad + bSrc[i] + offx, smem + 32768 + (w0 * 32 + i * 8) * 128);
        __syncthreads();
        #pragma unroll
        for (int kk = 0; kk < 2; ++kk) {
            const int ch = ((kk * 4 + lq) ^ (l & 7)) * 16;   // row&7 == l&7 for all frags
            bf16x8 a[4], b[8];
            #pragma unroll
            for (int i = 0; i < 4; ++i) a[i] = *(const bf16x8*)(smem + rowA[i] + ch);
            #pragma unroll
            for (int j = 0; j < 8; ++j) b[j] = *(const bf16x8*)(smem + rowB[j] + ch);
            #pragma unroll
            for (int ti = 0; ti < 4; ++ti)
                #pragma unroll
                for (int tj = 0; tj < 8; ++tj)
                    acc[ti][tj] = __builtin_amdgcn_mfma_f32_16x16x32_bf16(
                        a[ti], b[tj], acc[ti][tj], 0, 0, 0);
        }
        __syncthreads();
    }

    // ---- epilogue: C/D layout col=lane&15 (spatial), row=lq*4+r2 (out-ch) ----
    int obase[8];
    #pragma unroll
    for (int tj = 0; tj < 8; ++tj) {
        int p = p0 + tj * 16 + lm;
        int n = p / 3136; int rem = p - n * 3136;
        int h = rem / 56; int ww = rem - h * 56;
        obase[tj] = n * (K_OUT * 3136) + h * 56 + ww;
    }
    const int kb = w0 * 64 + lq * 4;
    #pragma unroll
    for (int ti = 0; ti < 4; ++ti)
        #pragma unroll
        for (int tj = 0; tj < 8; ++tj) {
            float* op = out + obase[tj] + (kb + ti * 16) * 3136;
            #pragma unroll
            for (int r2 = 0; r2 < 4; ++r2)
                op[r2 * 3136] = acc[ti][tj][r2];
        }
}

// ---------------- fallback (only if ws too small): naive fp32 direct conv ----------------
__global__ void conv_naive(const float* __restrict__ x, const float* __restrict__ W,
                           float* __restrict__ out, int total) {
    int idx = blockIdx.x * 256 + threadIdx.x;
    if (idx >= total) return;
    int n = idx / (K_OUT * 3136); int rem = idx - n * (K_OUT * 3136);
    int k = rem / 3136; rem -= k * 3136;
    int h = rem / 56; int w = rem - h * 56;
    float acc = 0.f;
    for (int c = 0; c < C_IN; ++c) {
        const float* xp = x + ((n * C_IN + c) * HW) * HW;
        const float* wp = W + (k * C_IN + c) * 9;
        #pragma unroll
        for (int r = 0; r < 3; ++r) {
            int hh = h + r - 1;
            if ((unsigned)hh >= HW) continue;
            #pragma unroll
            for (int s = 0; s < 3; ++s) {
                int ww = w + s - 1;
                if ((unsigned)ww >= HW) continue;
                acc += xp[hh * HW + ww] * wp[r * 3 + s];
            }
        }
    }
    out[idx] = acc;
}

extern "C" void kernel_launch(void* const* d_in, const int* in_sizes, int n_in,
                              void* d_out, int out_size, void* d_ws, size_t ws_size,
                              hipStream_t stream) {
    const float* x = (const float*)d_in[0];
    const float* W = (const float*)d_in[1];
    float* out = (float*)d_out;
    const size_t need = (size_t)XPAD_BYTES + WT_BYTES;
    if (ws_size >= need) {
        unsigned short* xpad = (unsigned short*)d_ws;
        unsigned short* Wt = (unsigned short*)((char*)d_ws + XPAD_BYTES);
        prep<<<PREP_BLOCKS, 256, 0, stream>>>(x, W, xpad, Wt);
        conv_gemm<<<SPATIAL / 128, 256, 0, stream>>>(xpad, Wt, out);
    } else {
        conv_naive<<<(OUT_ELEMS + 255) / 256, 256, 0, stream>>>(x, W, out, OUT_ELEMS);
    }
}